// Round 6
// baseline (408.853 us; speedup 1.0000x reference)
//
#include <hip/hip_runtime.h>

#define NN 100000
#define EE 600000
#define HH 128
#define GG 4000
#define TT 128
#define LDSROW 136   // 128 shorts + 8 pad (272 B, 16B-aligned, bank shift 4/row)

typedef short short8 __attribute__((ext_vector_type(8)));
typedef unsigned short ushort8v __attribute__((ext_vector_type(8)));
typedef float floatx4 __attribute__((ext_vector_type(4)));

static __device__ __forceinline__ float bf2f(unsigned short u) {
  union { unsigned int i; float f; } v; v.i = ((unsigned int)u) << 16; return v.f;
}
static __device__ __forceinline__ unsigned short f2bf(float f) {
  union { float f; unsigned int i; } v; v.f = f;
  unsigned int r = (v.i + 0x7FFFu + ((v.i >> 16) & 1u)) >> 16;   // RNE
  return (unsigned short)r;
}

// ---------------- degree count (int) ----------------
__global__ __launch_bounds__(256) void deg_count_k(const int* __restrict__ ei,
                                                   int* __restrict__ cnt) {
  int e = blockIdx.x * 256 + threadIdx.x;
  if (e < EE) atomicAdd(&cnt[ei[EE + e]], 1);   // dst row
}

// ---------------- CSR build: 3-kernel exclusive scan (+dinv fused) ----------
__global__ __launch_bounds__(256) void scan1_k(const int* __restrict__ cnt,
                                               int* __restrict__ ptr,
                                               int* __restrict__ bsum,
                                               float* __restrict__ dinv) {
  const int i = blockIdx.x * 256 + threadIdx.x;
  int v = (i < NN) ? cnt[i] : 0;
  if (i < NN) dinv[i] = rsqrtf((float)v + 1.0f);   // +1 self-loop
  const int lane = threadIdx.x & 63, wid = threadIdx.x >> 6;
  int s = v;
#pragma unroll
  for (int off = 1; off < 64; off <<= 1) {
    int t = __shfl_up(s, off, 64);
    if (lane >= off) s += t;
  }
  __shared__ int wt[4];
  if (lane == 63) wt[wid] = s;
  __syncthreads();
  int wadd = 0;
  for (int w = 0; w < wid; w++) wadd += wt[w];
  int incl = s + wadd;
  if (i < NN) ptr[i] = incl - v;
  if (threadIdx.x == 255) bsum[blockIdx.x] = incl;
}

__global__ __launch_bounds__(512) void scan2_k(int* __restrict__ bsum, int nb) {
  const int t = threadIdx.x;
  int v = (t < nb) ? bsum[t] : 0;
  const int lane = t & 63, wid = t >> 6;
  int s = v;
#pragma unroll
  for (int off = 1; off < 64; off <<= 1) {
    int u = __shfl_up(s, off, 64);
    if (lane >= off) s += u;
  }
  __shared__ int wt[8];
  if (lane == 63) wt[wid] = s;
  __syncthreads();
  int wadd = 0;
  for (int w = 0; w < wid; w++) wadd += wt[w];
  int incl = s + wadd;
  if (t < nb) bsum[t] = incl - v;
}

__global__ __launch_bounds__(256) void scan3_k(int* __restrict__ ptr,
                                               const int* __restrict__ bsum) {
  const int i = blockIdx.x * 256 + threadIdx.x;
  if (i < NN) ptr[i] += bsum[blockIdx.x];
  if (i == 0) ptr[NN] = EE;
}

__global__ __launch_bounds__(256) void fill_k(const int* __restrict__ ei,
                                              const int* __restrict__ ptr,
                                              int* __restrict__ cnt,
                                              int* __restrict__ csr) {
  int e = blockIdx.x * 256 + threadIdx.x;
  if (e >= EE) return;
  int d = ei[EE + e];
  int ofs = atomicSub(&cnt[d], 1) - 1;
  csr[ptr[d] + ofs] = ei[e];                     // store src
}

// ---------------- atom encoder -> pre-scaled Hs0 = bf16(dinv * h0) ----------
__global__ __launch_bounds__(256) void atom_enc_k(const int* __restrict__ x,
                                                  const float* __restrict__ emb,
                                                  const float* __restrict__ dinv,
                                                  unsigned short* __restrict__ h0) {
  const int lane = threadIdx.x & 63;
  const int wid  = threadIdx.x >> 6;
  const int l16  = lane & 15;
  const int n = blockIdx.x * 16 + wid * 4 + (lane >> 4);   // grid*16 == NN
  const int off[9] = {0, 119, 124, 136, 148, 158, 164, 170, 172};
  int xv = (l16 < 9) ? x[n * 9 + l16] : 0;
  float s[8] = {0.f, 0.f, 0.f, 0.f, 0.f, 0.f, 0.f, 0.f};
#pragma unroll
  for (int f = 0; f < 9; f++) {
    int idx = __shfl(xv, (lane & 48) | f, 64) + off[f];
    const float* ep = emb + (size_t)idx * HH + l16 * 8;
    float4 e0 = *(const float4*)ep;
    float4 e1 = *(const float4*)(ep + 4);
    s[0] += e0.x; s[1] += e0.y; s[2] += e0.z; s[3] += e0.w;
    s[4] += e1.x; s[5] += e1.y; s[6] += e1.z; s[7] += e1.w;
  }
  const float dv = dinv[n];
  ushort8v o;
#pragma unroll
  for (int j = 0; j < 8; j++) o[j] = f2bf(dv * s[j]);
  *(ushort8v*)(h0 + (size_t)n * HH + l16 * 8) = o;
}

// ---------------- weight transpose+convert (all 3): Wt[n][k] = bf16(W[k][n]) -
__global__ __launch_bounds__(128) void wtconv3_k(const float* __restrict__ W1,
                                                 const float* __restrict__ W2,
                                                 const float* __restrict__ W3,
                                                 unsigned short* __restrict__ Wt) {
  const int wsel = blockIdx.x >> 7;
  const int n = blockIdx.x & 127, k = threadIdx.x;
  const float* W = (wsel == 0) ? W1 : (wsel == 1) ? W2 : W3;
  Wt[wsel * HH * HH + n * HH + k] = f2bf(W[k * HH + n]);
}

// ---------------- fused layer: CSR aggregate (LDS) + MFMA GEMM --------------
// Aggs = dinv * (Hs[self] + sum_neighbors Hs[src])   (staged bf16 in LDS)
// C    = Aggs @ W + b
// LAST==false: Out = bf16(dinv * relu(C))   (pre-scaled for next layer)
// LAST==true : Out = bf16(C)
template <bool LAST>
__global__ __launch_bounds__(512) void layer_k(const int* __restrict__ ptr,
                                               const int* __restrict__ csr,
                                               const unsigned short* __restrict__ Hs,
                                               const float* __restrict__ dinv,
                                               const unsigned short* __restrict__ Wt,
                                               const float* __restrict__ b,
                                               unsigned short* __restrict__ Out) {
  __shared__ unsigned short sm[128 * LDSROW];   // 34 KB
  const int lane = threadIdx.x & 63;
  const int wid  = threadIdx.x >> 6;        // 0..7
  const int l16  = lane & 15;
  const int nq   = lane >> 4;               // 0..3
  const int bm   = blockIdx.x * 128;

  // ---- phase 1: aggregate this block's 128 rows into LDS ----
#pragma unroll
  for (int j = 0; j < 4; j++) {
    const int nb = j * 32 + wid * 4 + nq;
    const int n  = bm + nb;
    float acc[8] = {0.f, 0.f, 0.f, 0.f, 0.f, 0.f, 0.f, 0.f};
    if (n < NN) {
      ushort8v v = *(const ushort8v*)(Hs + (size_t)n * HH + l16 * 8);
#pragma unroll
      for (int c = 0; c < 8; c++) acc[c] = bf2f(v[c]);
      const int beg = ptr[n], end = ptr[n + 1];
      int i = beg;
      for (; i + 3 < end; i += 4) {
        int s0 = csr[i], s1 = csr[i + 1], s2 = csr[i + 2], s3 = csr[i + 3];
        ushort8v v0 = *(const ushort8v*)(Hs + (size_t)s0 * HH + l16 * 8);
        ushort8v v1 = *(const ushort8v*)(Hs + (size_t)s1 * HH + l16 * 8);
        ushort8v v2 = *(const ushort8v*)(Hs + (size_t)s2 * HH + l16 * 8);
        ushort8v v3 = *(const ushort8v*)(Hs + (size_t)s3 * HH + l16 * 8);
#pragma unroll
        for (int c = 0; c < 8; c++)
          acc[c] += (bf2f(v0[c]) + bf2f(v1[c])) + (bf2f(v2[c]) + bf2f(v3[c]));
      }
      for (; i < end; i++) {
        int s0 = csr[i];
        ushort8v v0 = *(const ushort8v*)(Hs + (size_t)s0 * HH + l16 * 8);
#pragma unroll
        for (int c = 0; c < 8; c++) acc[c] += bf2f(v0[c]);
      }
      const float dv = dinv[n];
#pragma unroll
      for (int c = 0; c < 8; c++) acc[c] *= dv;
    }
    ushort8v o;
#pragma unroll
    for (int c = 0; c < 8; c++) o[c] = f2bf(acc[c]);
    *(ushort8v*)(sm + nb * LDSROW + l16 * 8) = o;
  }
  __syncthreads();

  // ---- phase 2: [128x128] @ W via MFMA (A from LDS, B from L2) ----
  floatx4 acc2[8];
#pragma unroll
  for (int tn = 0; tn < 8; tn++) acc2[tn] = (floatx4){0.f, 0.f, 0.f, 0.f};

#pragma unroll
  for (int q = 0; q < 4; q++) {
    const int k0 = q * 32;
    short8 a = *(const short8*)((const short*)sm + (wid * 16 + l16) * LDSROW + k0 + nq * 8);
#pragma unroll
    for (int tn = 0; tn < 8; tn++) {
      short8 bf = *(const short8*)(Wt + (size_t)(tn * 16 + l16) * HH + k0 + nq * 8);
      acc2[tn] = __builtin_amdgcn_mfma_f32_16x16x32_bf16(a, bf, acc2[tn], 0, 0, 0);
    }
  }

  float bias[8];
#pragma unroll
  for (int tn = 0; tn < 8; tn++) bias[tn] = b[tn * 16 + l16];

  const int rbase = bm + wid * 16 + nq * 4;
#pragma unroll
  for (int r = 0; r < 4; r++) {
    const int row = rbase + r;
    if (row < NN) {
      const float dv = LAST ? 1.0f : dinv[row];
#pragma unroll
      for (int tn = 0; tn < 8; tn++) {
        float v = acc2[tn][r] + bias[tn];
        if (!LAST) v = dv * fmaxf(v, 0.f);
        Out[(size_t)row * HH + tn * 16 + l16] = f2bf(v);
      }
    }
  }
}

// ---------------- fused pool + final linear ----------------
__device__ inline int lbound(const int* __restrict__ b, int val) {
  int lo = 0, hi = NN;
  while (lo < hi) {
    int mid = (lo + hi) >> 1;
    if (b[mid] < val) lo = mid + 1; else hi = mid;
  }
  return lo;
}

__global__ __launch_bounds__(128) void pool_final_k(const int* __restrict__ batch,
                                                    const unsigned short* __restrict__ h3,
                                                    const float* __restrict__ Wl,
                                                    const float* __restrict__ bl,
                                                    float* __restrict__ out) {
  const int g = blockIdx.x;
  const int t = threadIdx.x;
  const int beg = lbound(batch, g);
  const int end = lbound(batch, g + 1);
  float s = 0.f;
  for (int n = beg; n < end; n++) s += bf2f(h3[(size_t)n * HH + t]);
  __shared__ float p[128];
  p[t] = s / (float)max(end - beg, 1);
  __syncthreads();
  float acc = bl[t];
#pragma unroll 8
  for (int h = 0; h < HH; h++) acc += p[h] * Wl[h * TT + t];
  out[(size_t)g * TT + t] = acc;
}

extern "C" void kernel_launch(void* const* d_in, const int* in_sizes, int n_in,
                              void* d_out, int out_size, void* d_ws, size_t ws_size,
                              hipStream_t stream) {
  const int*   x     = (const int*)d_in[0];
  const int*   ei    = (const int*)d_in[1];
  const int*   batch = (const int*)d_in[2];
  const float* emb   = (const float*)d_in[3];
  const float* W1    = (const float*)d_in[4];
  const float* b1    = (const float*)d_in[5];
  const float* W2    = (const float*)d_in[6];
  const float* b2    = (const float*)d_in[7];
  const float* W3    = (const float*)d_in[8];
  const float* b3    = (const float*)d_in[9];
  const float* Wl    = (const float*)d_in[10];
  const float* bl    = (const float*)d_in[11];
  float* out = (float*)d_out;

  // workspace layout (~57 MB)
  unsigned short* bufA = (unsigned short*)d_ws;        // N*H bf16
  unsigned short* bufB = bufA + (size_t)NN * HH;       // N*H bf16
  unsigned short* Wt   = bufB + (size_t)NN * HH;       // 3*H*H bf16
  float* dinv   = (float*)(Wt + 3 * HH * HH);          // N
  int*   ptr    = (int*)(dinv + NN);                   // N+1
  int*   cnt    = ptr + NN + 1;                        // N
  int*   bsum   = cnt + NN;                            // 512
  int*   csr    = bsum + 512;                          // E

  hipMemsetAsync(cnt, 0, NN * sizeof(int), stream);

  const int NB = (NN + 255) / 256;

  deg_count_k<<<(EE + 255) / 256, 256, 0, stream>>>(ei, cnt);
  scan1_k<<<NB, 256, 0, stream>>>(cnt, ptr, bsum, dinv);
  scan2_k<<<1, 512, 0, stream>>>(bsum, NB);
  scan3_k<<<NB, 256, 0, stream>>>(ptr, bsum);
  fill_k<<<(EE + 255) / 256, 256, 0, stream>>>(ei, ptr, cnt, csr);

  atom_enc_k<<<NN / 16, 256, 0, stream>>>(x, emb, dinv, bufA);
  wtconv3_k<<<3 * HH, HH, 0, stream>>>(W1, W2, W3, Wt);

  const int layer_grid = (NN + 127) / 128;   // 782

  layer_k<false><<<layer_grid, 512, 0, stream>>>(ptr, csr, bufA, dinv, Wt, b1, bufB);
  layer_k<false><<<layer_grid, 512, 0, stream>>>(ptr, csr, bufB, dinv, Wt + HH * HH, b2, bufA);
  layer_k<true><<<layer_grid, 512, 0, stream>>>(ptr, csr, bufA, dinv, Wt + 2 * HH * HH, b3, bufB);

  pool_final_k<<<GG, 128, 0, stream>>>(batch, bufB, Wl, bl, out);
}

// Round 7
// 405.643 us; speedup vs baseline: 1.0079x; 1.0079x over previous
//
#include <hip/hip_runtime.h>

#define NN 100000
#define EE 600000
#define HH 128
#define GG 4000
#define TT 128
#define LDSROW 136   // 128 shorts + 8 pad (272 B, 16B-aligned)

typedef short short8 __attribute__((ext_vector_type(8)));
typedef unsigned short ushort8v __attribute__((ext_vector_type(8)));
typedef float floatx4 __attribute__((ext_vector_type(4)));

static __device__ __forceinline__ float bf2f(unsigned short u) {
  union { unsigned int i; float f; } v; v.i = ((unsigned int)u) << 16; return v.f;
}
static __device__ __forceinline__ unsigned short f2bf(float f) {
  union { float f; unsigned int i; } v; v.f = f;
  unsigned int r = (v.i + 0x7FFFu + ((v.i >> 16) & 1u)) >> 16;   // RNE
  return (unsigned short)r;
}

// ---------------- degree count (int) ----------------
__global__ __launch_bounds__(256) void deg_count_k(const int* __restrict__ ei,
                                                   int* __restrict__ cnt) {
  int e = blockIdx.x * 256 + threadIdx.x;
  if (e < EE) atomicAdd(&cnt[ei[EE + e]], 1);   // dst row
}

// ---------------- CSR build: 3-kernel exclusive scan (+dinv fused) ----------
__global__ __launch_bounds__(256) void scan1_k(const int* __restrict__ cnt,
                                               int* __restrict__ ptr,
                                               int* __restrict__ bsum,
                                               float* __restrict__ dinv) {
  const int i = blockIdx.x * 256 + threadIdx.x;
  int v = (i < NN) ? cnt[i] : 0;
  if (i < NN) dinv[i] = rsqrtf((float)v + 1.0f);   // +1 self-loop
  const int lane = threadIdx.x & 63, wid = threadIdx.x >> 6;
  int s = v;
#pragma unroll
  for (int off = 1; off < 64; off <<= 1) {
    int t = __shfl_up(s, off, 64);
    if (lane >= off) s += t;
  }
  __shared__ int wt[4];
  if (lane == 63) wt[wid] = s;
  __syncthreads();
  int wadd = 0;
  for (int w = 0; w < wid; w++) wadd += wt[w];
  int incl = s + wadd;
  if (i < NN) ptr[i] = incl - v;
  if (threadIdx.x == 255) bsum[blockIdx.x] = incl;
}

__global__ __launch_bounds__(512) void scan2_k(int* __restrict__ bsum, int nb) {
  const int t = threadIdx.x;
  int v = (t < nb) ? bsum[t] : 0;
  const int lane = t & 63, wid = t >> 6;
  int s = v;
#pragma unroll
  for (int off = 1; off < 64; off <<= 1) {
    int u = __shfl_up(s, off, 64);
    if (lane >= off) s += u;
  }
  __shared__ int wt[8];
  if (lane == 63) wt[wid] = s;
  __syncthreads();
  int wadd = 0;
  for (int w = 0; w < wid; w++) wadd += wt[w];
  int incl = s + wadd;
  if (t < nb) bsum[t] = incl - v;
}

__global__ __launch_bounds__(256) void scan3_k(int* __restrict__ ptr,
                                               const int* __restrict__ bsum) {
  const int i = blockIdx.x * 256 + threadIdx.x;
  if (i < NN) ptr[i] += bsum[blockIdx.x];
  if (i == 0) ptr[NN] = EE;
}

__global__ __launch_bounds__(256) void fill_k(const int* __restrict__ ei,
                                              const int* __restrict__ ptr,
                                              int* __restrict__ cnt,
                                              int* __restrict__ csr) {
  int e = blockIdx.x * 256 + threadIdx.x;
  if (e >= EE) return;
  int d = ei[EE + e];
  int ofs = atomicSub(&cnt[d], 1) - 1;
  csr[ptr[d] + ofs] = ei[e];                     // store src
}

// ---------------- atom encoder -> pre-scaled Hs0 = bf16(dinv * h0) ----------
__global__ __launch_bounds__(256) void atom_enc_k(const int* __restrict__ x,
                                                  const float* __restrict__ emb,
                                                  const float* __restrict__ dinv,
                                                  unsigned short* __restrict__ h0) {
  const int lane = threadIdx.x & 63;
  const int wid  = threadIdx.x >> 6;
  const int l16  = lane & 15;
  const int n = blockIdx.x * 16 + wid * 4 + (lane >> 4);   // grid*16 == NN
  const int off[9] = {0, 119, 124, 136, 148, 158, 164, 170, 172};
  int xv = (l16 < 9) ? x[n * 9 + l16] : 0;
  float s[8] = {0.f, 0.f, 0.f, 0.f, 0.f, 0.f, 0.f, 0.f};
#pragma unroll
  for (int f = 0; f < 9; f++) {
    int idx = __shfl(xv, (lane & 48) | f, 64) + off[f];
    const float* ep = emb + (size_t)idx * HH + l16 * 8;
    float4 e0 = *(const float4*)ep;
    float4 e1 = *(const float4*)(ep + 4);
    s[0] += e0.x; s[1] += e0.y; s[2] += e0.z; s[3] += e0.w;
    s[4] += e1.x; s[5] += e1.y; s[6] += e1.z; s[7] += e1.w;
  }
  const float dv = dinv[n];
  ushort8v o;
#pragma unroll
  for (int j = 0; j < 8; j++) o[j] = f2bf(dv * s[j]);
  *(ushort8v*)(h0 + (size_t)n * HH + l16 * 8) = o;
}

// ---------------- weight transpose+convert (all 3): Wt[n][k] = bf16(W[k][n]) -
__global__ __launch_bounds__(128) void wtconv3_k(const float* __restrict__ W1,
                                                 const float* __restrict__ W2,
                                                 const float* __restrict__ W3,
                                                 unsigned short* __restrict__ Wt) {
  const int wsel = blockIdx.x >> 7;
  const int n = blockIdx.x & 127, k = threadIdx.x;
  const float* W = (wsel == 0) ? W1 : (wsel == 1) ? W2 : W3;
  Wt[wsel * HH * HH + n * HH + k] = f2bf(W[k * HH + n]);
}

// ---------------- fused layer: CSR aggregate (LDS) + MFMA GEMM --------------
// 256 threads / 64 nodes per block -> 8 blocks/CU (32 waves, full occupancy).
// Aggs = dinv * (Hs[self] + sum_neighbors Hs[src])   (staged bf16 in LDS)
// C    = Aggs @ W + b
// LAST==false: Out = bf16(dinv * relu(C))   (pre-scaled for next layer)
// LAST==true : Out = bf16(C)
template <bool LAST>
__global__ __launch_bounds__(256) void layer_k(const int* __restrict__ ptr,
                                               const int* __restrict__ csr,
                                               const unsigned short* __restrict__ Hs,
                                               const float* __restrict__ dinv,
                                               const unsigned short* __restrict__ Wt,
                                               const float* __restrict__ b,
                                               unsigned short* __restrict__ Out) {
  __shared__ unsigned short sm[64 * LDSROW];   // 17.4 KB
  const int lane = threadIdx.x & 63;
  const int wid  = threadIdx.x >> 6;        // 0..3
  const int l16  = lane & 15;
  const int nq   = lane >> 4;               // 0..3
  const int bm   = blockIdx.x * 64;

  // ---- phase 1: aggregate this block's 64 rows into LDS ----
#pragma unroll
  for (int j = 0; j < 4; j++) {
    const int nb = j * 16 + wid * 4 + nq;   // 0..63
    const int n  = bm + nb;
    float acc[8] = {0.f, 0.f, 0.f, 0.f, 0.f, 0.f, 0.f, 0.f};
    if (n < NN) {
      ushort8v v = *(const ushort8v*)(Hs + (size_t)n * HH + l16 * 8);
#pragma unroll
      for (int c = 0; c < 8; c++) acc[c] = bf2f(v[c]);
      const int beg = ptr[n], end = ptr[n + 1];
      int i = beg;
      for (; i + 3 < end; i += 4) {
        int s0 = csr[i], s1 = csr[i + 1], s2 = csr[i + 2], s3 = csr[i + 3];
        ushort8v v0 = *(const ushort8v*)(Hs + (size_t)s0 * HH + l16 * 8);
        ushort8v v1 = *(const ushort8v*)(Hs + (size_t)s1 * HH + l16 * 8);
        ushort8v v2 = *(const ushort8v*)(Hs + (size_t)s2 * HH + l16 * 8);
        ushort8v v3 = *(const ushort8v*)(Hs + (size_t)s3 * HH + l16 * 8);
#pragma unroll
        for (int c = 0; c < 8; c++)
          acc[c] += (bf2f(v0[c]) + bf2f(v1[c])) + (bf2f(v2[c]) + bf2f(v3[c]));
      }
      for (; i < end; i++) {
        int s0 = csr[i];
        ushort8v v0 = *(const ushort8v*)(Hs + (size_t)s0 * HH + l16 * 8);
#pragma unroll
        for (int c = 0; c < 8; c++) acc[c] += bf2f(v0[c]);
      }
      const float dv = dinv[n];
#pragma unroll
      for (int c = 0; c < 8; c++) acc[c] *= dv;
    }
    ushort8v o;
#pragma unroll
    for (int c = 0; c < 8; c++) o[c] = f2bf(acc[c]);
    *(ushort8v*)(sm + nb * LDSROW + l16 * 8) = o;
  }
  __syncthreads();

  // ---- phase 2: [64x128] @ W via MFMA (A from LDS, B from L2) ----
  // wave wid owns M-tile rows [wid*16, wid*16+16)
  floatx4 acc2[8];
#pragma unroll
  for (int tn = 0; tn < 8; tn++) acc2[tn] = (floatx4){0.f, 0.f, 0.f, 0.f};

#pragma unroll
  for (int q = 0; q < 4; q++) {
    const int k0 = q * 32;
    short8 a = *(const short8*)((const short*)sm + (wid * 16 + l16) * LDSROW + k0 + nq * 8);
#pragma unroll
    for (int tn = 0; tn < 8; tn++) {
      short8 bf = *(const short8*)(Wt + (size_t)(tn * 16 + l16) * HH + k0 + nq * 8);
      acc2[tn] = __builtin_amdgcn_mfma_f32_16x16x32_bf16(a, bf, acc2[tn], 0, 0, 0);
    }
  }

  float bias[8];
#pragma unroll
  for (int tn = 0; tn < 8; tn++) bias[tn] = b[tn * 16 + l16];

  const int rbase = bm + wid * 16 + nq * 4;
#pragma unroll
  for (int r = 0; r < 4; r++) {
    const int row = rbase + r;
    if (row < NN) {
      const float dv = LAST ? 1.0f : dinv[row];
#pragma unroll
      for (int tn = 0; tn < 8; tn++) {
        float v = acc2[tn][r] + bias[tn];
        if (!LAST) v = dv * fmaxf(v, 0.f);
        Out[(size_t)row * HH + tn * 16 + l16] = f2bf(v);
      }
    }
  }
}

// ---------------- fused pool + final linear ----------------
__device__ inline int lbound(const int* __restrict__ b, int val) {
  int lo = 0, hi = NN;
  while (lo < hi) {
    int mid = (lo + hi) >> 1;
    if (b[mid] < val) lo = mid + 1; else hi = mid;
  }
  return lo;
}

__global__ __launch_bounds__(128) void pool_final_k(const int* __restrict__ batch,
                                                    const unsigned short* __restrict__ h3,
                                                    const float* __restrict__ Wl,
                                                    const float* __restrict__ bl,
                                                    float* __restrict__ out) {
  const int g = blockIdx.x;
  const int t = threadIdx.x;
  const int beg = lbound(batch, g);
  const int end = lbound(batch, g + 1);
  float s = 0.f;
  for (int n = beg; n < end; n++) s += bf2f(h3[(size_t)n * HH + t]);
  __shared__ float p[128];
  p[t] = s / (float)max(end - beg, 1);
  __syncthreads();
  float acc = bl[t];
#pragma unroll 8
  for (int h = 0; h < HH; h++) acc += p[h] * Wl[h * TT + t];
  out[(size_t)g * TT + t] = acc;
}

extern "C" void kernel_launch(void* const* d_in, const int* in_sizes, int n_in,
                              void* d_out, int out_size, void* d_ws, size_t ws_size,
                              hipStream_t stream) {
  const int*   x     = (const int*)d_in[0];
  const int*   ei    = (const int*)d_in[1];
  const int*   batch = (const int*)d_in[2];
  const float* emb   = (const float*)d_in[3];
  const float* W1    = (const float*)d_in[4];
  const float* b1    = (const float*)d_in[5];
  const float* W2    = (const float*)d_in[6];
  const float* b2    = (const float*)d_in[7];
  const float* W3    = (const float*)d_in[8];
  const float* b3    = (const float*)d_in[9];
  const float* Wl    = (const float*)d_in[10];
  const float* bl    = (const float*)d_in[11];
  float* out = (float*)d_out;

  // workspace layout (~57 MB)
  unsigned short* bufA = (unsigned short*)d_ws;        // N*H bf16
  unsigned short* bufB = bufA + (size_t)NN * HH;       // N*H bf16
  unsigned short* Wt   = bufB + (size_t)NN * HH;       // 3*H*H bf16
  float* dinv   = (float*)(Wt + 3 * HH * HH);          // N
  int*   ptr    = (int*)(dinv + NN);                   // N+1
  int*   cnt    = ptr + NN + 1;                        // N
  int*   bsum   = cnt + NN;                            // 512
  int*   csr    = bsum + 512;                          // E

  hipMemsetAsync(cnt, 0, NN * sizeof(int), stream);

  const int NB = (NN + 255) / 256;

  deg_count_k<<<(EE + 255) / 256, 256, 0, stream>>>(ei, cnt);
  scan1_k<<<NB, 256, 0, stream>>>(cnt, ptr, bsum, dinv);
  scan2_k<<<1, 512, 0, stream>>>(bsum, NB);
  scan3_k<<<NB, 256, 0, stream>>>(ptr, bsum);
  fill_k<<<(EE + 255) / 256, 256, 0, stream>>>(ei, ptr, cnt, csr);

  atom_enc_k<<<NN / 16, 256, 0, stream>>>(x, emb, dinv, bufA);
  wtconv3_k<<<3 * HH, HH, 0, stream>>>(W1, W2, W3, Wt);

  const int layer_grid = (NN + 63) / 64;   // 1563

  layer_k<false><<<layer_grid, 256, 0, stream>>>(ptr, csr, bufA, dinv, Wt, b1, bufB);
  layer_k<false><<<layer_grid, 256, 0, stream>>>(ptr, csr, bufB, dinv, Wt + HH * HH, b2, bufA);
  layer_k<true><<<layer_grid, 256, 0, stream>>>(ptr, csr, bufA, dinv, Wt + 2 * HH * HH, b3, bufB);

  pool_final_k<<<GG, 128, 0, stream>>>(batch, bufB, Wl, bl, out);
}

// Round 8
// 363.917 us; speedup vs baseline: 1.1235x; 1.1147x over previous
//
#include <hip/hip_runtime.h>

#define NN 100000
#define EE 600000
#define HH 128
#define GG 4000
#define TT 128

typedef short short8 __attribute__((ext_vector_type(8)));
typedef unsigned short ushort8v __attribute__((ext_vector_type(8)));
typedef float floatx4 __attribute__((ext_vector_type(4)));

static __device__ __forceinline__ float bf2f(unsigned short u) {
  union { unsigned int i; float f; } v; v.i = ((unsigned int)u) << 16; return v.f;
}
static __device__ __forceinline__ unsigned short f2bf(float f) {
  union { float f; unsigned int i; } v; v.f = f;
  unsigned int r = (v.i + 0x7FFFu + ((v.i >> 16) & 1u)) >> 16;   // RNE
  return (unsigned short)r;
}

// ---------------- degree count (int) ----------------
__global__ __launch_bounds__(256) void deg_count_k(const int* __restrict__ ei,
                                                   int* __restrict__ cnt) {
  int e = blockIdx.x * 256 + threadIdx.x;
  if (e < EE) atomicAdd(&cnt[ei[EE + e]], 1);   // dst row
}

// ---------------- CSR build: 3-kernel exclusive scan (+dinv fused) ----------
__global__ __launch_bounds__(256) void scan1_k(const int* __restrict__ cnt,
                                               int* __restrict__ ptr,
                                               int* __restrict__ bsum,
                                               float* __restrict__ dinv) {
  const int i = blockIdx.x * 256 + threadIdx.x;
  int v = (i < NN) ? cnt[i] : 0;
  if (i < NN) dinv[i] = rsqrtf((float)v + 1.0f);   // +1 self-loop
  const int lane = threadIdx.x & 63, wid = threadIdx.x >> 6;
  int s = v;
#pragma unroll
  for (int off = 1; off < 64; off <<= 1) {
    int t = __shfl_up(s, off, 64);
    if (lane >= off) s += t;
  }
  __shared__ int wt[4];
  if (lane == 63) wt[wid] = s;
  __syncthreads();
  int wadd = 0;
  for (int w = 0; w < wid; w++) wadd += wt[w];
  int incl = s + wadd;
  if (i < NN) ptr[i] = incl - v;
  if (threadIdx.x == 255) bsum[blockIdx.x] = incl;
}

__global__ __launch_bounds__(512) void scan2_k(int* __restrict__ bsum, int nb) {
  const int t = threadIdx.x;
  int v = (t < nb) ? bsum[t] : 0;
  const int lane = t & 63, wid = t >> 6;
  int s = v;
#pragma unroll
  for (int off = 1; off < 64; off <<= 1) {
    int u = __shfl_up(s, off, 64);
    if (lane >= off) s += u;
  }
  __shared__ int wt[8];
  if (lane == 63) wt[wid] = s;
  __syncthreads();
  int wadd = 0;
  for (int w = 0; w < wid; w++) wadd += wt[w];
  int incl = s + wadd;
  if (t < nb) bsum[t] = incl - v;
}

// scan3 + graph-boundary precompute (batch is sorted):
// gs[g] = first node index of graph g; gs[GG] = NN.
__global__ __launch_bounds__(256) void scan3_gb_k(int* __restrict__ ptr,
                                                  const int* __restrict__ bsum,
                                                  const int* __restrict__ batch,
                                                  int* __restrict__ gs) {
  const int i = blockIdx.x * 256 + threadIdx.x;
  if (i < NN) {
    ptr[i] += bsum[blockIdx.x];
    int b0 = batch[i];
    int b1 = (i + 1 < NN) ? batch[i + 1] : GG;
    for (int g = b0 + 1; g <= b1; g++) gs[g] = i + 1;
    if (i == 0) {
      ptr[NN] = EE;
      for (int g = 0; g <= b0; g++) gs[g] = 0;
    }
  }
}

__global__ __launch_bounds__(256) void fill_k(const int* __restrict__ ei,
                                              const int* __restrict__ ptr,
                                              int* __restrict__ cnt,
                                              int* __restrict__ csr) {
  int e = blockIdx.x * 256 + threadIdx.x;
  if (e >= EE) return;
  int d = ei[EE + e];
  int ofs = atomicSub(&cnt[d], 1) - 1;
  csr[ptr[d] + ofs] = ei[e];                     // store src
}

// ---------------- atom encoder (-> Hs0 = bf16(dinv*h0)) + weight transpose --
// blocks [0, NN/16)          : atom encoder, 16 nodes/block
// blocks [NN/16, NN/16+192)  : Wt[n][k] = bf16(W[k][n]) for W1,W2,W3
__global__ __launch_bounds__(256) void enc_wt_k(const int* __restrict__ x,
                                                const float* __restrict__ emb,
                                                const float* __restrict__ dinv,
                                                unsigned short* __restrict__ h0,
                                                const float* __restrict__ W1,
                                                const float* __restrict__ W2,
                                                const float* __restrict__ W3,
                                                unsigned short* __restrict__ Wt) {
  if (blockIdx.x < NN / 16) {
    const int lane = threadIdx.x & 63;
    const int wid  = threadIdx.x >> 6;
    const int l16  = lane & 15;
    const int n = blockIdx.x * 16 + wid * 4 + (lane >> 4);
    const int off[9] = {0, 119, 124, 136, 148, 158, 164, 170, 172};
    int xv = (l16 < 9) ? x[n * 9 + l16] : 0;
    float s[8] = {0.f, 0.f, 0.f, 0.f, 0.f, 0.f, 0.f, 0.f};
#pragma unroll
    for (int f = 0; f < 9; f++) {
      int idx = __shfl(xv, (lane & 48) | f, 64) + off[f];
      const float* ep = emb + (size_t)idx * HH + l16 * 8;
      float4 e0 = *(const float4*)ep;
      float4 e1 = *(const float4*)(ep + 4);
      s[0] += e0.x; s[1] += e0.y; s[2] += e0.z; s[3] += e0.w;
      s[4] += e1.x; s[5] += e1.y; s[6] += e1.z; s[7] += e1.w;
    }
    const float dv = dinv[n];
    ushort8v o;
#pragma unroll
    for (int j = 0; j < 8; j++) o[j] = f2bf(dv * s[j]);
    *(ushort8v*)(h0 + (size_t)n * HH + l16 * 8) = o;
  } else {
    int f = (blockIdx.x - NN / 16) * 256 + threadIdx.x;   // 0..49151
    int wsel = f >> 14;
    int r = (f >> 7) & 127;
    int k = f & 127;
    const float* W = (wsel == 0) ? W1 : (wsel == 1) ? W2 : W3;
    Wt[wsel * HH * HH + r * HH + k] = f2bf(W[k * HH + r]);
  }
}

// ---------------- CSR aggregation (before GEMM) ----------------
// Aggs[n] = bf16( dinv[n] * (Hs[n] + sum_{s in in(n)} Hs[s]) )
__global__ __launch_bounds__(256) void agg_bf_k(const int* __restrict__ ptr,
                                                const int* __restrict__ csr,
                                                const unsigned short* __restrict__ Hs,
                                                const float* __restrict__ dinv,
                                                unsigned short* __restrict__ Aggs) {
  const int lane = threadIdx.x & 63;
  const int wid  = threadIdx.x >> 6;
  const int l16  = lane & 15;
  const int n = blockIdx.x * 16 + wid * 4 + (lane >> 4);   // grid*16 == NN
  const int beg = ptr[n], end = ptr[n + 1];
  float acc[8];
  {  // self row
    ushort8v v = *(const ushort8v*)(Hs + (size_t)n * HH + l16 * 8);
#pragma unroll
    for (int j = 0; j < 8; j++) acc[j] = bf2f(v[j]);
  }
  int i = beg;
  for (; i + 3 < end; i += 4) {
    int s0 = csr[i], s1 = csr[i + 1], s2 = csr[i + 2], s3 = csr[i + 3];
    ushort8v v0 = *(const ushort8v*)(Hs + (size_t)s0 * HH + l16 * 8);
    ushort8v v1 = *(const ushort8v*)(Hs + (size_t)s1 * HH + l16 * 8);
    ushort8v v2 = *(const ushort8v*)(Hs + (size_t)s2 * HH + l16 * 8);
    ushort8v v3 = *(const ushort8v*)(Hs + (size_t)s3 * HH + l16 * 8);
#pragma unroll
    for (int j = 0; j < 8; j++)
      acc[j] += (bf2f(v0[j]) + bf2f(v1[j])) + (bf2f(v2[j]) + bf2f(v3[j]));
  }
  for (; i < end; i++) {
    int s0 = csr[i];
    ushort8v v0 = *(const ushort8v*)(Hs + (size_t)s0 * HH + l16 * 8);
#pragma unroll
    for (int j = 0; j < 8; j++) acc[j] += bf2f(v0[j]);
  }
  const float dv = dinv[n];
  ushort8v o;
#pragma unroll
  for (int j = 0; j < 8; j++) o[j] = f2bf(dv * acc[j]);
  *(ushort8v*)(Aggs + (size_t)n * HH + l16 * 8) = o;
}

// ---------------- MFMA GEMM (after aggregation) ----------------
// C = Aggs @ W + b
// LAST==false: Hs_next = bf16(dinv * relu(C))   (pre-scaled for next agg)
// LAST==true : H3      = bf16(C)                (for pooling)
template <bool LAST>
__global__ __launch_bounds__(256) void gemm_mfma_k(const unsigned short* __restrict__ A,
                                                   const unsigned short* __restrict__ Wt,
                                                   const float* __restrict__ b,
                                                   const float* __restrict__ dinv,
                                                   unsigned short* __restrict__ Out) {
  const int w = threadIdx.x >> 6;
  const int l = threadIdx.x & 63;
  const int m16 = l & 15;
  const int q8  = (l >> 4) * 8;
  const int bm  = blockIdx.x * 128 + w * 32;

  floatx4 acc[2][8];
#pragma unroll
  for (int i = 0; i < 2; i++)
#pragma unroll
    for (int j = 0; j < 8; j++) acc[i][j] = (floatx4){0.f, 0.f, 0.f, 0.f};

  for (int q = 0; q < 4; q++) {
    const int k0 = q * 32;
    short8 a[2];
#pragma unroll
    for (int ti = 0; ti < 2; ti++) {
      int row = bm + ti * 16 + m16;
      a[ti] = (row < NN) ? *(const short8*)(A + (size_t)row * HH + k0 + q8)
                         : (short8){0, 0, 0, 0, 0, 0, 0, 0};
    }
#pragma unroll
    for (int tn = 0; tn < 8; tn++) {
      short8 bf = *(const short8*)(Wt + (size_t)(tn * 16 + m16) * HH + k0 + q8);
      acc[0][tn] = __builtin_amdgcn_mfma_f32_16x16x32_bf16(a[0], bf, acc[0][tn], 0, 0, 0);
      acc[1][tn] = __builtin_amdgcn_mfma_f32_16x16x32_bf16(a[1], bf, acc[1][tn], 0, 0, 0);
    }
  }

  float bias[8];
#pragma unroll
  for (int tn = 0; tn < 8; tn++) bias[tn] = b[tn * 16 + m16];

#pragma unroll
  for (int ti = 0; ti < 2; ti++) {
    const int rbase = bm + ti * 16 + (l >> 4) * 4;
#pragma unroll
    for (int r = 0; r < 4; r++) {
      const int row = rbase + r;
      if (row < NN) {
        const float dv = LAST ? 1.0f : dinv[row];
#pragma unroll
        for (int tn = 0; tn < 8; tn++) {
          const int col = tn * 16 + m16;
          float v = acc[ti][tn][r] + bias[tn];
          if (!LAST) v = dv * fmaxf(v, 0.f);
          Out[(size_t)row * HH + col] = f2bf(v);
        }
      }
    }
  }
}

// ---------------- fused pool + final linear (boundaries precomputed) --------
__global__ __launch_bounds__(128) void pool_final_k(const int* __restrict__ gs,
                                                    const unsigned short* __restrict__ h3,
                                                    const float* __restrict__ Wl,
                                                    const float* __restrict__ bl,
                                                    float* __restrict__ out) {
  const int g = blockIdx.x;
  const int t = threadIdx.x;
  const int beg = gs[g];
  const int end = gs[g + 1];
  float s = 0.f;
  for (int n = beg; n < end; n++) s += bf2f(h3[(size_t)n * HH + t]);
  __shared__ float p[128];
  p[t] = s / (float)max(end - beg, 1);
  __syncthreads();
  float acc = bl[t];
#pragma unroll 8
  for (int h = 0; h < HH; h++) acc += p[h] * Wl[h * TT + t];
  out[(size_t)g * TT + t] = acc;
}

extern "C" void kernel_launch(void* const* d_in, const int* in_sizes, int n_in,
                              void* d_out, int out_size, void* d_ws, size_t ws_size,
                              hipStream_t stream) {
  const int*   x     = (const int*)d_in[0];
  const int*   ei    = (const int*)d_in[1];
  const int*   batch = (const int*)d_in[2];
  const float* emb   = (const float*)d_in[3];
  const float* W1    = (const float*)d_in[4];
  const float* b1    = (const float*)d_in[5];
  const float* W2    = (const float*)d_in[6];
  const float* b2    = (const float*)d_in[7];
  const float* W3    = (const float*)d_in[8];
  const float* b3    = (const float*)d_in[9];
  const float* Wl    = (const float*)d_in[10];
  const float* bl    = (const float*)d_in[11];
  float* out = (float*)d_out;

  // workspace layout (~57 MB)
  unsigned short* bufA = (unsigned short*)d_ws;        // N*H bf16 (Hs / H3)
  unsigned short* bufB = bufA + (size_t)NN * HH;       // N*H bf16 (Aggs)
  unsigned short* Wt   = bufB + (size_t)NN * HH;       // 3*H*H bf16
  float* dinv   = (float*)(Wt + 3 * HH * HH);          // N
  int*   ptr    = (int*)(dinv + NN);                   // N+1
  int*   cnt    = ptr + NN + 1;                        // N
  int*   bsum   = cnt + NN;                            // 512
  int*   gs     = bsum + 512;                          // G+1
  int*   csr    = gs + GG + 1;                         // E

  hipMemsetAsync(cnt, 0, NN * sizeof(int), stream);

  const int NB = (NN + 255) / 256;

  deg_count_k<<<(EE + 255) / 256, 256, 0, stream>>>(ei, cnt);
  scan1_k<<<NB, 256, 0, stream>>>(cnt, ptr, bsum, dinv);
  scan2_k<<<1, 512, 0, stream>>>(bsum, NB);
  scan3_gb_k<<<NB, 256, 0, stream>>>(ptr, bsum, batch, gs);
  fill_k<<<(EE + 255) / 256, 256, 0, stream>>>(ei, ptr, cnt, csr);

  enc_wt_k<<<NN / 16 + 192, 256, 0, stream>>>(x, emb, dinv, bufA, W1, W2, W3, Wt);

  const int gemm_grid = (NN + 127) / 128;
  const int agg_grid  = NN / 16;   // NN % 16 == 0

  agg_bf_k<<<agg_grid, 256, 0, stream>>>(ptr, csr, bufA, dinv, bufB);
  gemm_mfma_k<false><<<gemm_grid, 256, 0, stream>>>(bufB, Wt, b1, dinv, bufA);

  agg_bf_k<<<agg_grid, 256, 0, stream>>>(ptr, csr, bufA, dinv, bufB);
  gemm_mfma_k<false><<<gemm_grid, 256, 0, stream>>>(bufB, Wt + HH * HH, b2, dinv, bufA);

  agg_bf_k<<<agg_grid, 256, 0, stream>>>(ptr, csr, bufA, dinv, bufB);
  gemm_mfma_k<true><<<gemm_grid, 256, 0, stream>>>(bufB, Wt + 2 * HH * HH, b3, dinv, bufA);

  pool_final_k<<<GG, 128, 0, stream>>>(gs, bufA, Wl, bl, out);
}

// Round 9
// 347.249 us; speedup vs baseline: 1.1774x; 1.0480x over previous
//
#include <hip/hip_runtime.h>

#define NN 100000
#define EE 600000
#define HH 128
#define GG 4000
#define TT 128

typedef short short8 __attribute__((ext_vector_type(8)));
typedef unsigned short ushort8v __attribute__((ext_vector_type(8)));
typedef float floatx4 __attribute__((ext_vector_type(4)));

static __device__ __forceinline__ float bf2f(unsigned short u) {
  union { unsigned int i; float f; } v; v.i = ((unsigned int)u) << 16; return v.f;
}
static __device__ __forceinline__ unsigned short f2bf(float f) {
  union { float f; unsigned int i; } v; v.f = f;
  unsigned int r = (v.i + 0x7FFFu + ((v.i >> 16) & 1u)) >> 16;   // RNE
  return (unsigned short)r;
}

// ---------------- degree count (int) ----------------
__global__ __launch_bounds__(256) void deg_count_k(const int* __restrict__ ei,
                                                   int* __restrict__ cnt) {
  int e = blockIdx.x * 256 + threadIdx.x;
  if (e < EE) atomicAdd(&cnt[ei[EE + e]], 1);   // dst row
}

// ---------------- CSR build: 3-kernel exclusive scan (+dinv fused) ----------
__global__ __launch_bounds__(256) void scan1_k(const int* __restrict__ cnt,
                                               int* __restrict__ ptr,
                                               int* __restrict__ bsum,
                                               float* __restrict__ dinv) {
  const int i = blockIdx.x * 256 + threadIdx.x;
  int v = (i < NN) ? cnt[i] : 0;
  if (i < NN) dinv[i] = rsqrtf((float)v + 1.0f);   // +1 self-loop
  const int lane = threadIdx.x & 63, wid = threadIdx.x >> 6;
  int s = v;
#pragma unroll
  for (int off = 1; off < 64; off <<= 1) {
    int t = __shfl_up(s, off, 64);
    if (lane >= off) s += t;
  }
  __shared__ int wt[4];
  if (lane == 63) wt[wid] = s;
  __syncthreads();
  int wadd = 0;
  for (int w = 0; w < wid; w++) wadd += wt[w];
  int incl = s + wadd;
  if (i < NN) ptr[i] = incl - v;
  if (threadIdx.x == 255) bsum[blockIdx.x] = incl;
}

__global__ __launch_bounds__(512) void scan2_k(int* __restrict__ bsum, int nb) {
  const int t = threadIdx.x;
  int v = (t < nb) ? bsum[t] : 0;
  const int lane = t & 63, wid = t >> 6;
  int s = v;
#pragma unroll
  for (int off = 1; off < 64; off <<= 1) {
    int u = __shfl_up(s, off, 64);
    if (lane >= off) s += u;
  }
  __shared__ int wt[8];
  if (lane == 63) wt[wid] = s;
  __syncthreads();
  int wadd = 0;
  for (int w = 0; w < wid; w++) wadd += wt[w];
  int incl = s + wadd;
  if (t < nb) bsum[t] = incl - v;
}

// scan3 + graph-boundary precompute (batch is sorted):
// gs[g] = first node index of graph g; gs[GG] = NN.
__global__ __launch_bounds__(256) void scan3_gb_k(int* __restrict__ ptr,
                                                  const int* __restrict__ bsum,
                                                  const int* __restrict__ batch,
                                                  int* __restrict__ gs) {
  const int i = blockIdx.x * 256 + threadIdx.x;
  if (i < NN) {
    ptr[i] += bsum[blockIdx.x];
    int b0 = batch[i];
    int b1 = (i + 1 < NN) ? batch[i + 1] : GG;
    for (int g = b0 + 1; g <= b1; g++) gs[g] = i + 1;
    if (i == 0) {
      ptr[NN] = EE;
      for (int g = 0; g <= b0; g++) gs[g] = 0;
    }
  }
}

// ---------------- merged: CSR fill + atom encoder + weight transpose --------
// blocks [0, FB)            : fill csr (cursor via atomicSub on cnt)
// blocks [FB, FB+NN/16)     : atom encoder -> Hs0 = bf16(dinv * h0)
// blocks [FB+NN/16, +192)   : Wt[n][k] = bf16(W[k][n]) for W1,W2,W3
#define FB ((EE + 255) / 256)
__global__ __launch_bounds__(256) void fill_enc_wt_k(const int* __restrict__ ei,
                                                     const int* __restrict__ ptr,
                                                     int* __restrict__ cnt,
                                                     int* __restrict__ csr,
                                                     const int* __restrict__ x,
                                                     const float* __restrict__ emb,
                                                     const float* __restrict__ dinv,
                                                     unsigned short* __restrict__ h0,
                                                     const float* __restrict__ W1,
                                                     const float* __restrict__ W2,
                                                     const float* __restrict__ W3,
                                                     unsigned short* __restrict__ Wt) {
  if (blockIdx.x < FB) {
    int e = blockIdx.x * 256 + threadIdx.x;
    if (e >= EE) return;
    int d = ei[EE + e];
    int ofs = atomicSub(&cnt[d], 1) - 1;
    csr[ptr[d] + ofs] = ei[e];                   // store src
  } else if (blockIdx.x < FB + NN / 16) {
    const int lane = threadIdx.x & 63;
    const int wid  = threadIdx.x >> 6;
    const int l16  = lane & 15;
    const int n = (blockIdx.x - FB) * 16 + wid * 4 + (lane >> 4);
    const int off[9] = {0, 119, 124, 136, 148, 158, 164, 170, 172};
    int xv = (l16 < 9) ? x[n * 9 + l16] : 0;
    float s[8] = {0.f, 0.f, 0.f, 0.f, 0.f, 0.f, 0.f, 0.f};
#pragma unroll
    for (int f = 0; f < 9; f++) {
      int idx = __shfl(xv, (lane & 48) | f, 64) + off[f];
      const float* ep = emb + (size_t)idx * HH + l16 * 8;
      float4 e0 = *(const float4*)ep;
      float4 e1 = *(const float4*)(ep + 4);
      s[0] += e0.x; s[1] += e0.y; s[2] += e0.z; s[3] += e0.w;
      s[4] += e1.x; s[5] += e1.y; s[6] += e1.z; s[7] += e1.w;
    }
    const float dv = dinv[n];
    ushort8v o;
#pragma unroll
    for (int j = 0; j < 8; j++) o[j] = f2bf(dv * s[j]);
    *(ushort8v*)(h0 + (size_t)n * HH + l16 * 8) = o;
  } else {
    int f = (blockIdx.x - FB - NN / 16) * 256 + threadIdx.x;   // 0..49151
    int wsel = f >> 14;
    int r = (f >> 7) & 127;
    int k = f & 127;
    const float* W = (wsel == 0) ? W1 : (wsel == 1) ? W2 : W3;
    Wt[wsel * HH * HH + r * HH + k] = f2bf(W[k * HH + r]);
  }
}

// ---------------- CSR aggregation (masked full-unroll, csr prefetch) --------
// Aggs[n] = bf16( dinv[n] * (Hs[n] + sum_{s in in(n)} Hs[s]) )
__global__ __launch_bounds__(256) void agg_bf_k(const int* __restrict__ ptr,
                                                const int* __restrict__ csr,
                                                const unsigned short* __restrict__ Hs,
                                                const float* __restrict__ dinv,
                                                unsigned short* __restrict__ Aggs) {
  const int lane = threadIdx.x & 63;
  const int wid  = threadIdx.x >> 6;
  const int l16  = lane & 15;
  const int n = blockIdx.x * 16 + wid * 4 + (lane >> 4);   // grid*16 == NN
  const int beg = ptr[n], end = ptr[n + 1];
  const int last = end - 1;
  float acc[8];
  {  // self row
    ushort8v v = *(const ushort8v*)(Hs + (size_t)n * HH + l16 * 8);
#pragma unroll
    for (int j = 0; j < 8; j++) acc[j] = bf2f(v[j]);
  }
  int i = beg;
  if (i < end) {
    int c0 = csr[i];
    int c1 = csr[min(i + 1, last)];
    int c2 = csr[min(i + 2, last)];
    int c3 = csr[min(i + 3, last)];
    while (true) {
      const float m1 = (i + 1 < end) ? 1.f : 0.f;
      const float m2 = (i + 2 < end) ? 1.f : 0.f;
      const float m3 = (i + 3 < end) ? 1.f : 0.f;
      ushort8v v0 = *(const ushort8v*)(Hs + (size_t)c0 * HH + l16 * 8);
      ushort8v v1 = *(const ushort8v*)(Hs + (size_t)c1 * HH + l16 * 8);
      ushort8v v2 = *(const ushort8v*)(Hs + (size_t)c2 * HH + l16 * 8);
      ushort8v v3 = *(const ushort8v*)(Hs + (size_t)c3 * HH + l16 * 8);
      const int ni = i + 4;
      int p0 = c0, p1 = c1, p2 = c2, p3 = c3;
      if (ni < end) {             // prefetch next csr quad (overlaps gathers)
        p0 = csr[ni];
        p1 = csr[min(ni + 1, last)];
        p2 = csr[min(ni + 2, last)];
        p3 = csr[min(ni + 3, last)];
      }
#pragma unroll
      for (int j = 0; j < 8; j++)
        acc[j] += bf2f(v0[j]) + m1 * bf2f(v1[j]) + m2 * bf2f(v2[j]) + m3 * bf2f(v3[j]);
      i = ni;
      if (i >= end) break;
      c0 = p0; c1 = p1; c2 = p2; c3 = p3;
    }
  }
  const float dv = dinv[n];
  ushort8v o;
#pragma unroll
  for (int j = 0; j < 8; j++) o[j] = f2bf(dv * acc[j]);
  *(ushort8v*)(Aggs + (size_t)n * HH + l16 * 8) = o;
}

// ---------------- MFMA GEMM (after aggregation) ----------------
// C = Aggs @ W + b
// LAST==false: Hs_next = bf16(dinv * relu(C))   (pre-scaled for next agg)
// LAST==true : H3      = bf16(C)                (for pooling)
template <bool LAST>
__global__ __launch_bounds__(256) void gemm_mfma_k(const unsigned short* __restrict__ A,
                                                   const unsigned short* __restrict__ Wt,
                                                   const float* __restrict__ b,
                                                   const float* __restrict__ dinv,
                                                   unsigned short* __restrict__ Out) {
  const int w = threadIdx.x >> 6;
  const int l = threadIdx.x & 63;
  const int m16 = l & 15;
  const int q8  = (l >> 4) * 8;
  const int bm  = blockIdx.x * 128 + w * 32;

  floatx4 acc[2][8];
#pragma unroll
  for (int i = 0; i < 2; i++)
#pragma unroll
    for (int j = 0; j < 8; j++) acc[i][j] = (floatx4){0.f, 0.f, 0.f, 0.f};

  for (int q = 0; q < 4; q++) {
    const int k0 = q * 32;
    short8 a[2];
#pragma unroll
    for (int ti = 0; ti < 2; ti++) {
      int row = bm + ti * 16 + m16;
      a[ti] = (row < NN) ? *(const short8*)(A + (size_t)row * HH + k0 + q8)
                         : (short8){0, 0, 0, 0, 0, 0, 0, 0};
    }
#pragma unroll
    for (int tn = 0; tn < 8; tn++) {
      short8 bf = *(const short8*)(Wt + (size_t)(tn * 16 + m16) * HH + k0 + q8);
      acc[0][tn] = __builtin_amdgcn_mfma_f32_16x16x32_bf16(a[0], bf, acc[0][tn], 0, 0, 0);
      acc[1][tn] = __builtin_amdgcn_mfma_f32_16x16x32_bf16(a[1], bf, acc[1][tn], 0, 0, 0);
    }
  }

  float bias[8];
#pragma unroll
  for (int tn = 0; tn < 8; tn++) bias[tn] = b[tn * 16 + m16];

#pragma unroll
  for (int ti = 0; ti < 2; ti++) {
    const int rbase = bm + ti * 16 + (l >> 4) * 4;
#pragma unroll
    for (int r = 0; r < 4; r++) {
      const int row = rbase + r;
      if (row < NN) {
        const float dv = LAST ? 1.0f : dinv[row];
#pragma unroll
        for (int tn = 0; tn < 8; tn++) {
          const int col = tn * 16 + m16;
          float v = acc[ti][tn][r] + bias[tn];
          if (!LAST) v = dv * fmaxf(v, 0.f);
          Out[(size_t)row * HH + col] = f2bf(v);
        }
      }
    }
  }
}

// ---------------- fused pool + final linear (boundaries precomputed) --------
__global__ __launch_bounds__(128) void pool_final_k(const int* __restrict__ gs,
                                                    const unsigned short* __restrict__ h3,
                                                    const float* __restrict__ Wl,
                                                    const float* __restrict__ bl,
                                                    float* __restrict__ out) {
  const int g = blockIdx.x;
  const int t = threadIdx.x;
  const int beg = gs[g];
  const int end = gs[g + 1];
  float s = 0.f;
  for (int n = beg; n < end; n++) s += bf2f(h3[(size_t)n * HH + t]);
  __shared__ float p[128];
  p[t] = s / (float)max(end - beg, 1);
  __syncthreads();
  float acc = bl[t];
#pragma unroll 8
  for (int h = 0; h < HH; h++) acc += p[h] * Wl[h * TT + t];
  out[(size_t)g * TT + t] = acc;
}

extern "C" void kernel_launch(void* const* d_in, const int* in_sizes, int n_in,
                              void* d_out, int out_size, void* d_ws, size_t ws_size,
                              hipStream_t stream) {
  const int*   x     = (const int*)d_in[0];
  const int*   ei    = (const int*)d_in[1];
  const int*   batch = (const int*)d_in[2];
  const float* emb   = (const float*)d_in[3];
  const float* W1    = (const float*)d_in[4];
  const float* b1    = (const float*)d_in[5];
  const float* W2    = (const float*)d_in[6];
  const float* b2    = (const float*)d_in[7];
  const float* W3    = (const float*)d_in[8];
  const float* b3    = (const float*)d_in[9];
  const float* Wl    = (const float*)d_in[10];
  const float* bl    = (const float*)d_in[11];
  float* out = (float*)d_out;

  // workspace layout (~57 MB)
  unsigned short* bufA = (unsigned short*)d_ws;        // N*H bf16 (Hs / H3)
  unsigned short* bufB = bufA + (size_t)NN * HH;       // N*H bf16 (Aggs)
  unsigned short* Wt   = bufB + (size_t)NN * HH;       // 3*H*H bf16
  float* dinv   = (float*)(Wt + 3 * HH * HH);          // N
  int*   ptr    = (int*)(dinv + NN);                   // N+1
  int*   cnt    = ptr + NN + 1;                        // N
  int*   bsum   = cnt + NN;                            // 512
  int*   gs     = bsum + 512;                          // G+1
  int*   csr    = gs + GG + 1;                         // E

  hipMemsetAsync(cnt, 0, NN * sizeof(int), stream);

  const int NB = (NN + 255) / 256;

  deg_count_k<<<(EE + 255) / 256, 256, 0, stream>>>(ei, cnt);
  scan1_k<<<NB, 256, 0, stream>>>(cnt, ptr, bsum, dinv);
  scan2_k<<<1, 512, 0, stream>>>(bsum, NB);
  scan3_gb_k<<<NB, 256, 0, stream>>>(ptr, bsum, batch, gs);
  fill_enc_wt_k<<<FB + NN / 16 + 192, 256, 0, stream>>>(ei, ptr, cnt, csr,
                                                        x, emb, dinv, bufA,
                                                        W1, W2, W3, Wt);

  const int gemm_grid = (NN + 127) / 128;
  const int agg_grid  = NN / 16;   // NN % 16 == 0

  agg_bf_k<<<agg_grid, 256, 0, stream>>>(ptr, csr, bufA, dinv, bufB);
  gemm_mfma_k<false><<<gemm_grid, 256, 0, stream>>>(bufB, Wt, b1, dinv, bufA);

  agg_bf_k<<<agg_grid, 256, 0, stream>>>(ptr, csr, bufA, dinv, bufB);
  gemm_mfma_k<false><<<gemm_grid, 256, 0, stream>>>(bufB, Wt + HH * HH, b2, dinv, bufA);

  agg_bf_k<<<agg_grid, 256, 0, stream>>>(ptr, csr, bufA, dinv, bufB);
  gemm_mfma_k<true><<<gemm_grid, 256, 0, stream>>>(bufB, Wt + 2 * HH * HH, b3, dinv, bufA);

  pool_final_k<<<GG, 128, 0, stream>>>(gs, bufA, Wl, bl, out);
}